// Round 12
// baseline (294.175 us; speedup 1.0000x reference)
//
#include <hip/hip_runtime.h>

typedef unsigned char uchar;
typedef unsigned short ushort;
typedef unsigned int uint;

constexpr int NN = 50000;
constexpr int NE = 1600000;
constexpr int NG = 1000;
constexpr int NB2 = 196;             // coarse buckets of 256 dst nodes
constexpr int TILE = 4096;           // bin_kernel tile (edges per block)
constexpr int NTILE = (NE + TILE - 1) / TILE;   // 391
constexpr int SPAN_CAP = 9216;       // bucket span cap (mean 8163, +11 sigma)
constexpr int MSTRIDE = 72;          // bf16 LDS row stride (64 + 8 pad)
constexpr int NPB = 16;              // aggr2: nodes per block-unit (4 waves x 4 groups)
constexpr int NBLK2 = NN / NPB;      // 3125 node-block units (NN % 16 == 0)
constexpr int GRID2 = 2048;          // aggr2 grid: 8 blocks/CU, grid-stride over NBLK2

// workspace layout in 4-byte units (R12 layout, P1+P2 fused into P12)
constexpr int OFF_BCNT  = 0;          // int[256]    (zeroed)
constexpr int OFF_SUMS  = 256;        // f32[64000]  (zeroed)
constexpr int OFF_CNT   = 64256;      // f32[1024]   (zeroed)
constexpr int ZERO_UNITS= 65280;
constexpr int OFF_BBASE = 65280;      // int[256]
constexpr int OFF_BCUR  = 65536;      // int[256]
constexpr int OFF_OFFS  = 65792;      // int[50176]
constexpr int OFF_P0    = 116224;     // uint[NE]   src | dstloc<<16 | bucket<<24
constexpr int OFF_P12   = 1716224;    // uint[2*NE] interleaved {ea01, ea23} bf16x2
constexpr int OFF_Z1    = 4916224;    // f32[NN*8]  (16B-aligned)
constexpr int OFF_H1    = 5316224;    // uint[NN*32] packed bf16 h1
constexpr int OFF_Z     = 6916224;    // uint[NN*32] packed bf16 z (16B-aligned)
// end = 8,516,224 units = 34.1 MB

typedef __attribute__((ext_vector_type(8))) short short8;
typedef __attribute__((ext_vector_type(4))) float float4v;
typedef __attribute__((ext_vector_type(2))) float float2v;
typedef __attribute__((ext_vector_type(2))) uint uint2v;

__device__ __forceinline__ uint f2bf(float f) {
    uint u = __float_as_uint(f);
    return (u + 0x7fffu + ((u >> 16) & 1u)) >> 16;
}
__device__ __forceinline__ float bf2f_lo(uint p) { return __uint_as_float(p << 16); }
__device__ __forceinline__ float bf2f_hi(uint p) { return __uint_as_float(p & 0xffff0000u); }

// ---------- coarse-bucket histogram ----------
__global__ __launch_bounds__(256) void bhist_kernel(const int* __restrict__ eidx,
                                                    int* __restrict__ bcnt) {
    __shared__ int lh[NB2];
    for (int i = threadIdx.x; i < NB2; i += 256) lh[i] = 0;
    __syncthreads();
    int tid = blockIdx.x * 256 + threadIdx.x;
    int stride = gridDim.x * 256;
    for (int e = tid; e < NE; e += stride) atomicAdd(&lh[eidx[NE + e] >> 8], 1);
    __syncthreads();
    for (int i = threadIdx.x; i < NB2; i += 256) if (lh[i]) atomicAdd(&bcnt[i], lh[i]);
}

// ---------- bucket scan ----------
__global__ __launch_bounds__(256) void bscan_kernel(const int* __restrict__ bcnt,
                                                    int* __restrict__ bbase,
                                                    int* __restrict__ bcur) {
    __shared__ int s[256];
    int t = threadIdx.x;
    int v = (t < NB2) ? bcnt[t] : 0;
    s[t] = v; __syncthreads();
    for (int o = 1; o < 256; o <<= 1) {
        int u = (t >= o) ? s[t - o] : 0;
        __syncthreads();
        s[t] += u;
        __syncthreads();
    }
    bbase[t] = s[t] - v;
    bcur[t] = s[t] - v;
}

// ---------- phase 1: bin edges into coarse buckets ----------
__global__ __launch_bounds__(256) void bin_kernel(const int* __restrict__ eidx,
                                                  const float4* __restrict__ ea,
                                                  int* __restrict__ bcur,
                                                  uint* __restrict__ p0,
                                                  uint* __restrict__ p12) {
    __shared__ uint s0[TILE], s1[TILE], s2[TILE];
    __shared__ int hcnt[NB2], hoff[NB2 + 1], hcur[NB2], gbase[NB2];
    const int t = threadIdx.x;
    const int e0 = blockIdx.x * TILE;
    const int cnt = (NE - e0 < TILE) ? (NE - e0) : TILE;
    for (int i = t; i < NB2; i += 256) hcnt[i] = 0;
    __syncthreads();
    int dsts[16];
    #pragma unroll
    for (int k = 0; k < 16; ++k) {
        int i = t + k * 256;
        int d = (i < cnt) ? eidx[NE + e0 + i] : -1;
        dsts[k] = d;
        if (d >= 0) atomicAdd(&hcnt[d >> 8], 1);
    }
    __syncthreads();
    if (t == 0) {
        int a = 0;
        for (int b = 0; b < NB2; ++b) { hoff[b] = a; a += hcnt[b]; }
        hoff[NB2] = a;
    }
    __syncthreads();
    if (t < NB2) { hcur[t] = hoff[t]; gbase[t] = atomicAdd(&bcur[t], hcnt[t]); }
    __syncthreads();
    #pragma unroll
    for (int k = 0; k < 16; ++k) {
        int d = dsts[k];
        if (d < 0) continue;
        int i = t + k * 256;
        int e = e0 + i;
        int src = eidx[e];
        float4 a = ea[e];
        int bkt = d >> 8;
        int lp = atomicAdd(&hcur[bkt], 1);
        s0[lp] = (uint)src | ((uint)(d & 255) << 16) | ((uint)bkt << 24);  // bucket in spare byte
        s1[lp] = f2bf(a.x) | (f2bf(a.y) << 16);
        s2[lp] = f2bf(a.z) | (f2bf(a.w) << 16);
    }
    __syncthreads();
    for (int i = t; i < cnt; i += 256) {            // no binary search: bucket id from s0 top byte
        uint r0 = s0[i];
        int bkt = (int)(r0 >> 24);
        int gp = gbase[bkt] + (i - hoff[bkt]);
        p0[gp] = r0;
        uint2 pv; pv.x = s1[i]; pv.y = s2[i];
        *(uint2*)&p12[2 * (size_t)gp] = pv;
    }
}

// ---------- phase 2: per-bucket degrees + offs + in-place permute (R12-proven) ----------
__global__ __launch_bounds__(256) void build_kernel(const int* __restrict__ bbase,
                                                    const int* __restrict__ bcnt,
                                                    int* __restrict__ offs,
                                                    uint* __restrict__ p0,
                                                    uint* __restrict__ p12) {
    __shared__ uint s0[SPAN_CAP], s1[SPAN_CAP], s2[SPAN_CAP];
    __shared__ int ldeg[256], lcur[256], sscan[256];
    const int t = threadIdx.x;
    const int b = blockIdx.x;
    const int nlo = b << 8;
    const int base = bbase[b];
    int span = bcnt[b];
    if (span > SPAN_CAP) span = SPAN_CAP;
    ldeg[t] = 0;
    __syncthreads();
    for (int i = t; i < span; i += 256)
        atomicAdd(&ldeg[(p0[base + i] >> 16) & 0xFFu], 1);
    __syncthreads();
    int v = ldeg[t];
    sscan[t] = v; __syncthreads();
    for (int o = 1; o < 256; o <<= 1) {
        int u = (t >= o) ? sscan[t - o] : 0;
        __syncthreads();
        sscan[t] += u;
        __syncthreads();
    }
    int exc = sscan[t] - v;
    lcur[t] = exc;
    int gi = nlo + t;
    if (gi < NN) offs[gi] = base + exc;
    else if (gi < 50176) offs[gi] = NE;
    __syncthreads();
    for (int i = t; i < span; i += 256) {
        uint r0 = p0[base + i];
        uint2 pv = *(const uint2*)&p12[2 * (size_t)(base + i)];
        int pos = atomicAdd(&lcur[(r0 >> 16) & 0xFFu], 1);
        s0[pos] = r0; s1[pos] = pv.x; s2[pos] = pv.y;
    }
    __syncthreads();
    for (int i = t; i < span; i += 256) {
        p0[base + i] = s0[i];
        uint2 pv; pv.x = s1[i]; pv.y = s2[i];
        *(uint2*)&p12[2 * (size_t)(base + i)] = pv;
    }
}

// ---------- Layer 1 aggregation (R12-proven structure, p12 merged loads) ----------
__global__ __launch_bounds__(256) void aggr1_kernel(
    const float* __restrict__ x,
    const uint* __restrict__ p0, const uint* __restrict__ p12,
    const int* __restrict__ offs,
    const float* __restrict__ We1, const float* __restrict__ be1,
    float* __restrict__ z1)
{
    __shared__ float sWe[32];
    __shared__ float sbe[8];
    int tid = threadIdx.x;
    if (tid < 32) { int k = tid >> 3, dd = tid & 7; sWe[tid] = (dd < 7) ? We1[k * 7 + dd] : 0.f; }
    if (tid < 8)  sbe[tid] = (tid < 7) ? be1[tid] : 0.f;
    __syncthreads();

    const int w = tid >> 6, lane = tid & 63;
    const int jg = lane >> 3, d = lane & 7;

    for (int n = blockIdx.x * 4 + w; n < NN; n += gridDim.x * 4) {
        const int off = offs[n];
        const int deg = offs[n + 1] - off;
        float acc = 0.f;
        for (int j0 = 0; j0 < deg; j0 += 16) {
            int ja = j0 + jg;
            int jb = j0 + 8 + jg;
            int ia = off + ((ja < deg) ? ja : 0);
            int ib = off + ((jb < deg) ? jb : 0);
            uint r0a = p0[ia];
            uint2 pa = *(const uint2*)&p12[2 * (size_t)ia];
            uint r0b = p0[ib];
            uint2 pb = *(const uint2*)&p12[2 * (size_t)ib];
            float xa = (d < 7) ? x[(size_t)(r0a & 0xFFFFu) * 7 + d] : 0.f;
            float xb = (d < 7) ? x[(size_t)(r0b & 0xFFFFu) * 7 + d] : 0.f;
            float va = sbe[d] + bf2f_lo(pa.x) * sWe[d] + bf2f_hi(pa.x) * sWe[8 + d]
                     + bf2f_lo(pa.y) * sWe[16 + d] + bf2f_hi(pa.y) * sWe[24 + d] + xa;
            float vb = sbe[d] + bf2f_lo(pb.x) * sWe[d] + bf2f_hi(pb.x) * sWe[8 + d]
                     + bf2f_lo(pb.y) * sWe[16 + d] + bf2f_hi(pb.y) * sWe[24 + d] + xb;
            va = (d < 7 && ja < deg) ? fmaxf(va, 0.f) : 0.f;
            vb = (d < 7 && jb < deg) ? fmaxf(vb, 0.f) : 0.f;
            acc += va + vb;
        }
        acc += __shfl_xor(acc, 8);
        acc += __shfl_xor(acc, 16);
        acc += __shfl_xor(acc, 32);
        if (jg == 0)
            z1[(size_t)n * 8 + d] = (d < 7) ? (x[(size_t)n * 7 + d] + acc) : 0.f;
    }
}

// ---------- node-1 MLP via MFMA (R12-proven) ----------
__global__ __launch_bounds__(256) void node1_kernel(
    const float* __restrict__ z1,
    const float* __restrict__ W1a, const float* __restrict__ b1a,
    const float* __restrict__ W1b, const float* __restrict__ b1b,
    uint* __restrict__ h1u)
{
    __shared__ __align__(16) ushort sT[64 * MSTRIDE];
    __shared__ __align__(16) ushort sO[64 * 64];
    const int t = threadIdx.x;
    const int w = t >> 6, lane = t & 63;
    const int qm = lane & 15, quad = lane >> 4;
    const int n0 = blockIdx.x * 64;
    const int node = n0 + w * 16 + qm;

    short8 wa1n[4];
    #pragma unroll
    for (int nt = 0; nt < 4; ++nt) {
        short8 v = (short8)0;
        if (quad == 0) {
            #pragma unroll
            for (int j = 0; j < 7; ++j)
                v[j] = (short)f2bf(W1a[j * 64 + nt * 16 + qm]);
        }
        wa1n[nt] = v;
    }
    short8 wb1[2][4];
    #pragma unroll
    for (int s = 0; s < 2; ++s)
        #pragma unroll
        for (int nt = 0; nt < 4; ++nt) {
            short8 v;
            #pragma unroll
            for (int j = 0; j < 8; ++j)
                v[j] = (short)f2bf(W1b[(s * 32 + quad * 8 + j) * 64 + nt * 16 + qm]);
            wb1[s][nt] = v;
        }
    float ba[4], bb[4];
    #pragma unroll
    for (int nt = 0; nt < 4; ++nt) { ba[nt] = b1a[nt * 16 + qm]; bb[nt] = b1b[nt * 16 + qm]; }

    short8 af1 = (short8)0;
    if (quad == 0 && node < NN) {
        const float4 za = *(const float4*)(z1 + (size_t)node * 8);
        const float4 zbv = *(const float4*)(z1 + (size_t)node * 8 + 4);
        af1[0] = (short)f2bf(za.x); af1[1] = (short)f2bf(za.y);
        af1[2] = (short)f2bf(za.z); af1[3] = (short)f2bf(za.w);
        af1[4] = (short)f2bf(zbv.x); af1[5] = (short)f2bf(zbv.y);
        af1[6] = (short)f2bf(zbv.z); af1[7] = (short)f2bf(zbv.w);
    }
    float4v acc[4];
    #pragma unroll
    for (int nt = 0; nt < 4; ++nt) {
        acc[nt] = (float4v){0.f, 0.f, 0.f, 0.f};
        acc[nt] = __builtin_amdgcn_mfma_f32_16x16x32_bf16(af1, wa1n[nt], acc[nt], 0, 0, 0);
    }
    #pragma unroll
    for (int nt = 0; nt < 4; ++nt)
        #pragma unroll
        for (int r = 0; r < 4; ++r)
            sT[(w * 16 + quad * 4 + r) * MSTRIDE + nt * 16 + qm] =
                (ushort)f2bf(fmaxf(acc[nt][r] + ba[nt], 0.f));
    __syncthreads();

    #pragma unroll
    for (int nt = 0; nt < 4; ++nt) acc[nt] = (float4v){0.f, 0.f, 0.f, 0.f};
    #pragma unroll
    for (int s = 0; s < 2; ++s) {
        short8 af = *(const short8*)&sT[(w * 16 + qm) * MSTRIDE + s * 32 + quad * 8];
        #pragma unroll
        for (int nt = 0; nt < 4; ++nt)
            acc[nt] = __builtin_amdgcn_mfma_f32_16x16x32_bf16(af, wb1[s][nt], acc[nt], 0, 0, 0);
    }
    #pragma unroll
    for (int nt = 0; nt < 4; ++nt)
        #pragma unroll
        for (int r = 0; r < 4; ++r)
            sO[(w * 16 + quad * 4 + r) * 64 + nt * 16 + qm] =
                (ushort)f2bf(fmaxf(acc[nt][r] + bb[nt], 0.f));
    __syncthreads();
    for (int i = t; i < 64 * 32; i += 256) {
        int nd = i >> 5;
        if (n0 + nd < NN) h1u[(size_t)(n0 + nd) * 32 + (i & 31)] = ((const uint*)sO)[i];
    }
}

// ---------- Layer 2 aggregation: node-per-16-lane-group, 4 ch/lane (R10 base),
// p12 merged loads + dmin full/tail split + grid-stride at 8 blocks/CU
// + NON-TEMPORAL loads on the single-use p0/p12 streams so they do not
// evict the reused h1u gather target from L2 (latency fix, not BW fix).
__global__ __launch_bounds__(256) void aggr2_kernel(
    const uint* __restrict__ h1u,
    const uint* __restrict__ p0, const uint* __restrict__ p12,
    const int* __restrict__ offs,
    const float* __restrict__ We2, const float* __restrict__ be2,
    uint* __restrict__ zb)
{
    const int tid = threadIdx.x;
    const int lane = tid & 63;
    const int wv = tid >> 6;             // wave 0..3
    const int grp = lane >> 4;           // node group 0..3 within wave
    const int cl = lane & 15;            // channel quad: ch 4cl..4cl+3

    // per-lane weights: columns 4cl..4cl+3 of We2[4][64], as 2 float2v per row
    float2v wA[4], wB[4], bA, bB;
    #pragma unroll
    for (int k = 0; k < 4; ++k) {
        const float4 w4 = *(const float4*)&We2[k * 64 + 4 * cl];
        wA[k][0] = w4.x; wA[k][1] = w4.y;
        wB[k][0] = w4.z; wB[k][1] = w4.w;
    }
    {
        const float4 b4 = *(const float4*)&be2[4 * cl];
        bA[0] = b4.x; bA[1] = b4.y;
        bB[0] = b4.z; bB[1] = b4.w;
    }

    #define EDGE_MATH(pey, pez, gg, tAo, tBo)                               \
    {                                                                       \
        float2v bvA = bA + bf2f_lo(pey) * wA[0] + bf2f_hi(pey) * wA[1]      \
                    + bf2f_lo(pez) * wA[2] + bf2f_hi(pez) * wA[3];          \
        float2v bvB = bB + bf2f_lo(pey) * wB[0] + bf2f_hi(pey) * wB[1]      \
                    + bf2f_lo(pez) * wB[2] + bf2f_hi(pez) * wB[3];          \
        tAo[0] = fmaxf(bf2f_lo((gg).x) + bvA[0], 0.f);                      \
        tAo[1] = fmaxf(bf2f_hi((gg).x) + bvA[1], 0.f);                      \
        tBo[0] = fmaxf(bf2f_lo((gg).y) + bvB[0], 0.f);                      \
        tBo[1] = fmaxf(bf2f_hi((gg).y) + bvB[1], 0.f);                      \
    }
    // non-temporal stream loads (single-use data; keep L2 for h1u)
    #define NTL_U32(p)  __builtin_nontemporal_load(p)
    #define NTL_U64(p)  __builtin_nontemporal_load((const uint2v*)(p))

    for (int nb = blockIdx.x; nb < NBLK2; nb += GRID2) {
        const int n = nb * NPB + wv * 4 + grp;   // NN % 16 == 0, always valid

        const int off = offs[n];
        const int deg = offs[n + 1] - off;
        const int degm1 = (deg > 0) ? deg - 1 : 0;
        const int offC = (deg > 0) ? off : 0;    // deg==0: clamp to a safe index
        // wave-uniform bounds: min/max degree over the wave's 4 groups
        int dmax = deg, dmin = deg;
        dmax = max(dmax, __shfl_xor(dmax, 16));
        dmax = max(dmax, __shfl_xor(dmax, 32));
        dmin = min(dmin, __shfl_xor(dmin, 16));
        dmin = min(dmin, __shfl_xor(dmin, 32));

        float2v accA = {0.f, 0.f}, accB = {0.f, 0.f};
        const float2v zero2 = {0.f, 0.f};

        int j = 0;
        // full phase: all 4 groups in-range, no clamping, no predication
        for (; j + 2 <= dmin; j += 2) {
            const int e0 = off + j, e1 = off + j + 1;
            const uint r00 = NTL_U32(p0 + e0);
            const uint2v pe0 = NTL_U64(p12 + 2 * (size_t)e0);
            const uint r01 = NTL_U32(p0 + e1);
            const uint2v pe1 = NTL_U64(p12 + 2 * (size_t)e1);
            const uint2 g0 = *(const uint2*)&h1u[((size_t)(r00 & 0xFFFFu) << 5) + 2 * cl];
            const uint2 g1 = *(const uint2*)&h1u[((size_t)(r01 & 0xFFFFu) << 5) + 2 * cl];
            float2v tA, tB;
            EDGE_MATH(pe0[0], pe0[1], g0, tA, tB);
            accA += tA; accB += tB;
            EDGE_MATH(pe1[0], pe1[1], g1, tA, tB);
            accA += tA; accB += tB;
        }
        // tail phase: predicated (j in [full-end, dmax))
        for (; j + 2 <= dmax; j += 2) {
            const bool q0 = (j < deg), q1 = (j + 1 < deg);
            const int e0 = offC + (q0 ? j : degm1);
            const int e1 = offC + (q1 ? j + 1 : degm1);
            const uint r00 = NTL_U32(p0 + e0);
            const uint2v pe0 = NTL_U64(p12 + 2 * (size_t)e0);
            const uint r01 = NTL_U32(p0 + e1);
            const uint2v pe1 = NTL_U64(p12 + 2 * (size_t)e1);
            const uint2 g0 = *(const uint2*)&h1u[((size_t)(r00 & 0xFFFFu) << 5) + 2 * cl];
            const uint2 g1 = *(const uint2*)&h1u[((size_t)(r01 & 0xFFFFu) << 5) + 2 * cl];
            float2v tA, tB;
            EDGE_MATH(pe0[0], pe0[1], g0, tA, tB);
            accA += q0 ? tA : zero2;
            accB += q0 ? tB : zero2;
            EDGE_MATH(pe1[0], pe1[1], g1, tA, tB);
            accA += q1 ? tA : zero2;
            accB += q1 ? tB : zero2;
        }
        if (j < dmax) {                           // odd remainder step
            const bool q0 = (j < deg);
            const int e0 = offC + (q0 ? j : degm1);
            const uint r00 = NTL_U32(p0 + e0);
            const uint2v pe0 = NTL_U64(p12 + 2 * (size_t)e0);
            const uint2 g0 = *(const uint2*)&h1u[((size_t)(r00 & 0xFFFFu) << 5) + 2 * cl];
            float2v tA, tB;
            EDGE_MATH(pe0[0], pe0[1], g0, tA, tB);
            accA += q0 ? tA : zero2;
            accB += q0 ? tB : zero2;
        }

        // epilogue: z = h1[n] + acc, pack bf16x2, store 2 dwords per lane
        // (consecutive groups = consecutive nodes -> contiguous 256B per wave)
        const uint2 hw = *(const uint2*)&h1u[(size_t)n * 32 + 2 * cl];
        uint o0 = f2bf(bf2f_lo(hw.x) + accA[0]) | (f2bf(bf2f_hi(hw.x) + accA[1]) << 16);
        uint o1 = f2bf(bf2f_lo(hw.y) + accB[0]) | (f2bf(bf2f_hi(hw.y) + accB[1]) << 16);
        uint2 ov; ov.x = o0; ov.y = o1;
        *(uint2*)&zb[(size_t)n * 32 + 2 * cl] = ov;
    }
    #undef EDGE_MATH
    #undef NTL_U32
    #undef NTL_U64
}

// ---------- Layer 2 MLP via MFMA + segmented-reduction pooling (R12-proven) ----------
__global__ __launch_bounds__(256) void mlp2_kernel(
    const uint* __restrict__ zb,
    const float* __restrict__ W2a, const float* __restrict__ b2a,
    const float* __restrict__ W2b, const float* __restrict__ b2b,
    const int* __restrict__ batch,
    float* __restrict__ sums, float* __restrict__ cnt)
{
    __shared__ __align__(16) ushort sT[64 * MSTRIDE];
    __shared__ float sH[64 * 64];
    __shared__ int sB[64];
    __shared__ float pbuf[4][64];
    __shared__ int pcnt[4];
    const int t = threadIdx.x;
    const int w = t >> 6, lane = t & 63;
    const int qm = lane & 15, quad = lane >> 4;
    const int n0 = blockIdx.x * 64;
    const int node = n0 + w * 16 + qm;
    const int nv = (NN - n0 < 64) ? (NN - n0) : 64;

    if (t < 64) sB[t] = (n0 + t < NN) ? batch[n0 + t] : -2;

    short8 wa[2][4], wb[2][4];
    #pragma unroll
    for (int s = 0; s < 2; ++s)
        #pragma unroll
        for (int nt = 0; nt < 4; ++nt) {
            short8 va, vb;
            #pragma unroll
            for (int j = 0; j < 8; ++j) {
                int k = s * 32 + quad * 8 + j, n = nt * 16 + qm;
                va[j] = (short)f2bf(W2a[k * 64 + n]);
                vb[j] = (short)f2bf(W2b[k * 64 + n]);
            }
            wa[s][nt] = va; wb[s][nt] = vb;
        }
    float ba[4], bb[4];
    #pragma unroll
    for (int nt = 0; nt < 4; ++nt) { ba[nt] = b2a[nt * 16 + qm]; bb[nt] = b2b[nt * 16 + qm]; }

    float4v acc[4];
    #pragma unroll
    for (int nt = 0; nt < 4; ++nt) acc[nt] = (float4v){0.f, 0.f, 0.f, 0.f};
    #pragma unroll
    for (int s = 0; s < 2; ++s) {
        uint4 zw = (node < NN) ? *(const uint4*)&zb[(size_t)node * 32 + s * 16 + quad * 4]
                               : make_uint4(0, 0, 0, 0);
        short8 af;
        *(uint4*)&af = zw;
        #pragma unroll
        for (int nt = 0; nt < 4; ++nt)
            acc[nt] = __builtin_amdgcn_mfma_f32_16x16x32_bf16(af, wa[s][nt], acc[nt], 0, 0, 0);
    }
    #pragma unroll
    for (int nt = 0; nt < 4; ++nt)
        #pragma unroll
        for (int r = 0; r < 4; ++r)
            sT[(w * 16 + quad * 4 + r) * MSTRIDE + nt * 16 + qm] =
                (ushort)f2bf(fmaxf(acc[nt][r] + ba[nt], 0.f));
    __syncthreads();

    #pragma unroll
    for (int nt = 0; nt < 4; ++nt) acc[nt] = (float4v){0.f, 0.f, 0.f, 0.f};
    #pragma unroll
    for (int s = 0; s < 2; ++s) {
        short8 af = *(const short8*)&sT[(w * 16 + qm) * MSTRIDE + s * 32 + quad * 8];
        #pragma unroll
        for (int nt = 0; nt < 4; ++nt)
            acc[nt] = __builtin_amdgcn_mfma_f32_16x16x32_bf16(af, wb[s][nt], acc[nt], 0, 0, 0);
    }
    #pragma unroll
    for (int nt = 0; nt < 4; ++nt)
        #pragma unroll
        for (int r = 0; r < 4; ++r)
            sH[(w * 16 + quad * 4 + r) * 64 + nt * 16 + qm] = fmaxf(acc[nt][r] + bb[nt], 0.f);
    __syncthreads();

    const int glo = sB[0];
    const int ghi = sB[nv - 1];
    const int c = t >> 6, d = t & 63;
    for (int g = glo; g <= ghi; ++g) {
        float p = 0.f;
        int lc = 0;
        #pragma unroll 4
        for (int i = 0; i < 16; ++i) {
            int nd = c * 16 + i;
            if (sB[nd] == g) { p += sH[nd * 64 + d]; ++lc; }
        }
        pbuf[c][d] = p;
        if (d == 0) pcnt[c] = lc;
        __syncthreads();
        int tc = pcnt[0] + pcnt[1] + pcnt[2] + pcnt[3];
        if (tc > 0) {
            if (c == 0) {
                float tot = pbuf[0][d] + pbuf[1][d] + pbuf[2][d] + pbuf[3][d];
                atomicAdd(&sums[(size_t)g * 64 + d], tot);
            }
            if (t == 0) atomicAdd(&cnt[g], (float)tc);
        }
        __syncthreads();
    }
}

// ---------- FC ----------
__global__ __launch_bounds__(256) void fc_kernel(
    const float* __restrict__ sums, const float* __restrict__ cnt,
    const float* __restrict__ Wfc, const float* __restrict__ bfc,
    float* __restrict__ out)
{
    int gid = blockIdx.x * blockDim.x + threadIdx.x;
    if (gid >= NG * 12) return;
    int g = gid / 12, jj = gid - g * 12;
    float inv = 1.f / fmaxf(cnt[g], 1.f);
    float acc = bfc[jj];
    #pragma unroll 8
    for (int k = 0; k < 64; ++k) acc += sums[(size_t)g * 64 + k] * inv * Wfc[k * 12 + jj];
    out[gid] = acc;
}

extern "C" void kernel_launch(void* const* d_in, const int* in_sizes, int n_in,
                              void* d_out, int out_size, void* d_ws, size_t ws_size,
                              hipStream_t stream)
{
    (void)in_sizes; (void)n_in; (void)out_size; (void)ws_size;
    const float*  x    = (const float*)d_in[0];
    const float4* ea   = (const float4*)d_in[1];
    const int*    eidx = (const int*)d_in[2];
    const int*    batch= (const int*)d_in[3];
    const float*  We1  = (const float*)d_in[4];
    const float*  be1  = (const float*)d_in[5];
    const float*  W1a  = (const float*)d_in[6];
    const float*  b1a  = (const float*)d_in[7];
    const float*  W1b  = (const float*)d_in[8];
    const float*  b1b  = (const float*)d_in[9];
    const float*  We2  = (const float*)d_in[10];
    const float*  be2  = (const float*)d_in[11];
    const float*  W2a  = (const float*)d_in[12];
    const float*  b2a  = (const float*)d_in[13];
    const float*  W2b  = (const float*)d_in[14];
    const float*  b2b  = (const float*)d_in[15];
    const float*  Wfc  = (const float*)d_in[16];
    const float*  bfc  = (const float*)d_in[17];
    float* out = (float*)d_out;
    float* ws  = (float*)d_ws;

    int*   bcnt  = (int*)(ws + OFF_BCNT);
    float* sums  = ws + OFF_SUMS;
    float* cnt   = ws + OFF_CNT;
    int*   bbase = (int*)(ws + OFF_BBASE);
    int*   bcur  = (int*)(ws + OFF_BCUR);
    int*   offs  = (int*)(ws + OFF_OFFS);
    uint*  p0    = (uint*)(ws + OFF_P0);
    uint*  p12   = (uint*)(ws + OFF_P12);
    float* z1    = ws + OFF_Z1;
    uint*  h1u   = (uint*)(ws + OFF_H1);
    uint*  zb    = (uint*)(ws + OFF_Z);

    hipMemsetAsync(d_ws, 0, (size_t)ZERO_UNITS * 4, stream);

    bhist_kernel<<<256, 256, 0, stream>>>(eidx, bcnt);
    bscan_kernel<<<1, 256, 0, stream>>>(bcnt, bbase, bcur);
    bin_kernel  <<<NTILE, 256, 0, stream>>>(eidx, ea, bcur, p0, p12);
    build_kernel<<<NB2, 256, 0, stream>>>(bbase, bcnt, offs, p0, p12);
    aggr1_kernel<<<2500, 256, 0, stream>>>(x, p0, p12, offs, We1, be1, z1);
    node1_kernel<<<(NN + 63) / 64, 256, 0, stream>>>(z1, W1a, b1a, W1b, b1b, h1u);
    aggr2_kernel<<<GRID2, 256, 0, stream>>>(h1u, p0, p12, offs, We2, be2, zb);
    mlp2_kernel <<<(NN + 63) / 64, 256, 0, stream>>>(zb, W2a, b2a, W2b, b2b, batch, sums, cnt);
    fc_kernel   <<<(NG * 12 + 255) / 256, 256, 0, stream>>>(sums, cnt, Wfc, bfc, out);
}

// Round 13
// 274.015 us; speedup vs baseline: 1.0736x; 1.0736x over previous
//
#include <hip/hip_runtime.h>

typedef unsigned char uchar;
typedef unsigned short ushort;
typedef unsigned int uint;

constexpr int NN = 50000;
constexpr int NE = 1600000;
constexpr int NG = 1000;
constexpr int NB2 = 196;             // coarse buckets of 256 dst nodes
constexpr int TILE = 4096;           // bin_kernel tile (edges per block)
constexpr int NTILE = (NE + TILE - 1) / TILE;   // 391
constexpr int SPAN_CAP = 9216;       // bucket span cap (mean 8163, +11 sigma)
constexpr int MSTRIDE = 72;          // bf16 LDS row stride (64 + 8 pad)
constexpr int NPB = 16;              // aggr2: nodes per block-unit (4 waves x 4 groups)
constexpr int NBLK2 = NN / NPB;      // 3125 node-block units (NN % 16 == 0)
constexpr int GRID2 = 2048;          // aggr2 grid: 8 blocks/CU, grid-stride over NBLK2

// workspace layout in 4-byte units (R12 layout, P1+P2 fused into P12)
constexpr int OFF_BCNT  = 0;          // int[256]    (zeroed)
constexpr int OFF_SUMS  = 256;        // f32[64000]  (zeroed)
constexpr int OFF_CNT   = 64256;      // f32[1024]   (zeroed)
constexpr int ZERO_UNITS= 65280;
constexpr int OFF_BBASE = 65280;      // int[256]
constexpr int OFF_BCUR  = 65536;      // int[256]
constexpr int OFF_OFFS  = 65792;      // int[50176]
constexpr int OFF_P0    = 116224;     // uint[NE]   src | dstloc<<16 | bucket<<24
constexpr int OFF_P12   = 1716224;    // uint[2*NE] interleaved {ea01, ea23} bf16x2
constexpr int OFF_Z1    = 4916224;    // f32[NN*8]  (16B-aligned)
constexpr int OFF_H1    = 5316224;    // uint[NN*32] packed bf16 h1
constexpr int OFF_Z     = 6916224;    // uint[NN*32] packed bf16 z (16B-aligned)
// end = 8,516,224 units = 34.1 MB

typedef __attribute__((ext_vector_type(8))) short short8;
typedef __attribute__((ext_vector_type(4))) float float4v;
typedef __attribute__((ext_vector_type(2))) float float2v;

__device__ __forceinline__ uint f2bf(float f) {
    uint u = __float_as_uint(f);
    return (u + 0x7fffu + ((u >> 16) & 1u)) >> 16;
}
__device__ __forceinline__ float bf2f_lo(uint p) { return __uint_as_float(p << 16); }
__device__ __forceinline__ float bf2f_hi(uint p) { return __uint_as_float(p & 0xffff0000u); }

// ---------- coarse-bucket histogram ----------
__global__ __launch_bounds__(256) void bhist_kernel(const int* __restrict__ eidx,
                                                    int* __restrict__ bcnt) {
    __shared__ int lh[NB2];
    for (int i = threadIdx.x; i < NB2; i += 256) lh[i] = 0;
    __syncthreads();
    int tid = blockIdx.x * 256 + threadIdx.x;
    int stride = gridDim.x * 256;
    for (int e = tid; e < NE; e += stride) atomicAdd(&lh[eidx[NE + e] >> 8], 1);
    __syncthreads();
    for (int i = threadIdx.x; i < NB2; i += 256) if (lh[i]) atomicAdd(&bcnt[i], lh[i]);
}

// ---------- bucket scan ----------
__global__ __launch_bounds__(256) void bscan_kernel(const int* __restrict__ bcnt,
                                                    int* __restrict__ bbase,
                                                    int* __restrict__ bcur) {
    __shared__ int s[256];
    int t = threadIdx.x;
    int v = (t < NB2) ? bcnt[t] : 0;
    s[t] = v; __syncthreads();
    for (int o = 1; o < 256; o <<= 1) {
        int u = (t >= o) ? s[t - o] : 0;
        __syncthreads();
        s[t] += u;
        __syncthreads();
    }
    bbase[t] = s[t] - v;
    bcur[t] = s[t] - v;
}

// ---------- phase 1: bin edges into coarse buckets ----------
__global__ __launch_bounds__(256) void bin_kernel(const int* __restrict__ eidx,
                                                  const float4* __restrict__ ea,
                                                  int* __restrict__ bcur,
                                                  uint* __restrict__ p0,
                                                  uint* __restrict__ p12) {
    __shared__ uint s0[TILE], s1[TILE], s2[TILE];
    __shared__ int hcnt[NB2], hoff[NB2 + 1], hcur[NB2], gbase[NB2];
    const int t = threadIdx.x;
    const int e0 = blockIdx.x * TILE;
    const int cnt = (NE - e0 < TILE) ? (NE - e0) : TILE;
    for (int i = t; i < NB2; i += 256) hcnt[i] = 0;
    __syncthreads();
    int dsts[16];
    #pragma unroll
    for (int k = 0; k < 16; ++k) {
        int i = t + k * 256;
        int d = (i < cnt) ? eidx[NE + e0 + i] : -1;
        dsts[k] = d;
        if (d >= 0) atomicAdd(&hcnt[d >> 8], 1);
    }
    __syncthreads();
    if (t == 0) {
        int a = 0;
        for (int b = 0; b < NB2; ++b) { hoff[b] = a; a += hcnt[b]; }
        hoff[NB2] = a;
    }
    __syncthreads();
    if (t < NB2) { hcur[t] = hoff[t]; gbase[t] = atomicAdd(&bcur[t], hcnt[t]); }
    __syncthreads();
    #pragma unroll
    for (int k = 0; k < 16; ++k) {
        int d = dsts[k];
        if (d < 0) continue;
        int i = t + k * 256;
        int e = e0 + i;
        int src = eidx[e];
        float4 a = ea[e];
        int bkt = d >> 8;
        int lp = atomicAdd(&hcur[bkt], 1);
        s0[lp] = (uint)src | ((uint)(d & 255) << 16) | ((uint)bkt << 24);  // bucket in spare byte
        s1[lp] = f2bf(a.x) | (f2bf(a.y) << 16);
        s2[lp] = f2bf(a.z) | (f2bf(a.w) << 16);
    }
    __syncthreads();
    for (int i = t; i < cnt; i += 256) {            // no binary search: bucket id from s0 top byte
        uint r0 = s0[i];
        int bkt = (int)(r0 >> 24);
        int gp = gbase[bkt] + (i - hoff[bkt]);
        p0[gp] = r0;
        uint2 pv; pv.x = s1[i]; pv.y = s2[i];
        *(uint2*)&p12[2 * (size_t)gp] = pv;
    }
}

// ---------- phase 2: per-bucket degrees + offs + in-place permute (R12-proven) ----------
__global__ __launch_bounds__(256) void build_kernel(const int* __restrict__ bbase,
                                                    const int* __restrict__ bcnt,
                                                    int* __restrict__ offs,
                                                    uint* __restrict__ p0,
                                                    uint* __restrict__ p12) {
    __shared__ uint s0[SPAN_CAP], s1[SPAN_CAP], s2[SPAN_CAP];
    __shared__ int ldeg[256], lcur[256], sscan[256];
    const int t = threadIdx.x;
    const int b = blockIdx.x;
    const int nlo = b << 8;
    const int base = bbase[b];
    int span = bcnt[b];
    if (span > SPAN_CAP) span = SPAN_CAP;
    ldeg[t] = 0;
    __syncthreads();
    for (int i = t; i < span; i += 256)
        atomicAdd(&ldeg[(p0[base + i] >> 16) & 0xFFu], 1);
    __syncthreads();
    int v = ldeg[t];
    sscan[t] = v; __syncthreads();
    for (int o = 1; o < 256; o <<= 1) {
        int u = (t >= o) ? sscan[t - o] : 0;
        __syncthreads();
        sscan[t] += u;
        __syncthreads();
    }
    int exc = sscan[t] - v;
    lcur[t] = exc;
    int gi = nlo + t;
    if (gi < NN) offs[gi] = base + exc;
    else if (gi < 50176) offs[gi] = NE;
    __syncthreads();
    for (int i = t; i < span; i += 256) {
        uint r0 = p0[base + i];
        uint2 pv = *(const uint2*)&p12[2 * (size_t)(base + i)];
        int pos = atomicAdd(&lcur[(r0 >> 16) & 0xFFu], 1);
        s0[pos] = r0; s1[pos] = pv.x; s2[pos] = pv.y;
    }
    __syncthreads();
    for (int i = t; i < span; i += 256) {
        p0[base + i] = s0[i];
        uint2 pv; pv.x = s1[i]; pv.y = s2[i];
        *(uint2*)&p12[2 * (size_t)(base + i)] = pv;
    }
}

// ---------- Layer 1 aggregation (R12-proven structure, p12 merged loads) ----------
__global__ __launch_bounds__(256) void aggr1_kernel(
    const float* __restrict__ x,
    const uint* __restrict__ p0, const uint* __restrict__ p12,
    const int* __restrict__ offs,
    const float* __restrict__ We1, const float* __restrict__ be1,
    float* __restrict__ z1)
{
    __shared__ float sWe[32];
    __shared__ float sbe[8];
    int tid = threadIdx.x;
    if (tid < 32) { int k = tid >> 3, dd = tid & 7; sWe[tid] = (dd < 7) ? We1[k * 7 + dd] : 0.f; }
    if (tid < 8)  sbe[tid] = (tid < 7) ? be1[tid] : 0.f;
    __syncthreads();

    const int w = tid >> 6, lane = tid & 63;
    const int jg = lane >> 3, d = lane & 7;

    for (int n = blockIdx.x * 4 + w; n < NN; n += gridDim.x * 4) {
        const int off = offs[n];
        const int deg = offs[n + 1] - off;
        float acc = 0.f;
        for (int j0 = 0; j0 < deg; j0 += 16) {
            int ja = j0 + jg;
            int jb = j0 + 8 + jg;
            int ia = off + ((ja < deg) ? ja : 0);
            int ib = off + ((jb < deg) ? jb : 0);
            uint r0a = p0[ia];
            uint2 pa = *(const uint2*)&p12[2 * (size_t)ia];
            uint r0b = p0[ib];
            uint2 pb = *(const uint2*)&p12[2 * (size_t)ib];
            float xa = (d < 7) ? x[(size_t)(r0a & 0xFFFFu) * 7 + d] : 0.f;
            float xb = (d < 7) ? x[(size_t)(r0b & 0xFFFFu) * 7 + d] : 0.f;
            float va = sbe[d] + bf2f_lo(pa.x) * sWe[d] + bf2f_hi(pa.x) * sWe[8 + d]
                     + bf2f_lo(pa.y) * sWe[16 + d] + bf2f_hi(pa.y) * sWe[24 + d] + xa;
            float vb = sbe[d] + bf2f_lo(pb.x) * sWe[d] + bf2f_hi(pb.x) * sWe[8 + d]
                     + bf2f_lo(pb.y) * sWe[16 + d] + bf2f_hi(pb.y) * sWe[24 + d] + xb;
            va = (d < 7 && ja < deg) ? fmaxf(va, 0.f) : 0.f;
            vb = (d < 7 && jb < deg) ? fmaxf(vb, 0.f) : 0.f;
            acc += va + vb;
        }
        acc += __shfl_xor(acc, 8);
        acc += __shfl_xor(acc, 16);
        acc += __shfl_xor(acc, 32);
        if (jg == 0)
            z1[(size_t)n * 8 + d] = (d < 7) ? (x[(size_t)n * 7 + d] + acc) : 0.f;
    }
}

// ---------- node-1 MLP via MFMA (R12-proven) ----------
__global__ __launch_bounds__(256) void node1_kernel(
    const float* __restrict__ z1,
    const float* __restrict__ W1a, const float* __restrict__ b1a,
    const float* __restrict__ W1b, const float* __restrict__ b1b,
    uint* __restrict__ h1u)
{
    __shared__ __align__(16) ushort sT[64 * MSTRIDE];
    __shared__ __align__(16) ushort sO[64 * 64];
    const int t = threadIdx.x;
    const int w = t >> 6, lane = t & 63;
    const int qm = lane & 15, quad = lane >> 4;
    const int n0 = blockIdx.x * 64;
    const int node = n0 + w * 16 + qm;

    short8 wa1n[4];
    #pragma unroll
    for (int nt = 0; nt < 4; ++nt) {
        short8 v = (short8)0;
        if (quad == 0) {
            #pragma unroll
            for (int j = 0; j < 7; ++j)
                v[j] = (short)f2bf(W1a[j * 64 + nt * 16 + qm]);
        }
        wa1n[nt] = v;
    }
    short8 wb1[2][4];
    #pragma unroll
    for (int s = 0; s < 2; ++s)
        #pragma unroll
        for (int nt = 0; nt < 4; ++nt) {
            short8 v;
            #pragma unroll
            for (int j = 0; j < 8; ++j)
                v[j] = (short)f2bf(W1b[(s * 32 + quad * 8 + j) * 64 + nt * 16 + qm]);
            wb1[s][nt] = v;
        }
    float ba[4], bb[4];
    #pragma unroll
    for (int nt = 0; nt < 4; ++nt) { ba[nt] = b1a[nt * 16 + qm]; bb[nt] = b1b[nt * 16 + qm]; }

    short8 af1 = (short8)0;
    if (quad == 0 && node < NN) {
        const float4 za = *(const float4*)(z1 + (size_t)node * 8);
        const float4 zbv = *(const float4*)(z1 + (size_t)node * 8 + 4);
        af1[0] = (short)f2bf(za.x); af1[1] = (short)f2bf(za.y);
        af1[2] = (short)f2bf(za.z); af1[3] = (short)f2bf(za.w);
        af1[4] = (short)f2bf(zbv.x); af1[5] = (short)f2bf(zbv.y);
        af1[6] = (short)f2bf(zbv.z); af1[7] = (short)f2bf(zbv.w);
    }
    float4v acc[4];
    #pragma unroll
    for (int nt = 0; nt < 4; ++nt) {
        acc[nt] = (float4v){0.f, 0.f, 0.f, 0.f};
        acc[nt] = __builtin_amdgcn_mfma_f32_16x16x32_bf16(af1, wa1n[nt], acc[nt], 0, 0, 0);
    }
    #pragma unroll
    for (int nt = 0; nt < 4; ++nt)
        #pragma unroll
        for (int r = 0; r < 4; ++r)
            sT[(w * 16 + quad * 4 + r) * MSTRIDE + nt * 16 + qm] =
                (ushort)f2bf(fmaxf(acc[nt][r] + ba[nt], 0.f));
    __syncthreads();

    #pragma unroll
    for (int nt = 0; nt < 4; ++nt) acc[nt] = (float4v){0.f, 0.f, 0.f, 0.f};
    #pragma unroll
    for (int s = 0; s < 2; ++s) {
        short8 af = *(const short8*)&sT[(w * 16 + qm) * MSTRIDE + s * 32 + quad * 8];
        #pragma unroll
        for (int nt = 0; nt < 4; ++nt)
            acc[nt] = __builtin_amdgcn_mfma_f32_16x16x32_bf16(af, wb1[s][nt], acc[nt], 0, 0, 0);
    }
    #pragma unroll
    for (int nt = 0; nt < 4; ++nt)
        #pragma unroll
        for (int r = 0; r < 4; ++r)
            sO[(w * 16 + quad * 4 + r) * 64 + nt * 16 + qm] =
                (ushort)f2bf(fmaxf(acc[nt][r] + bb[nt], 0.f));
    __syncthreads();
    for (int i = t; i < 64 * 32; i += 256) {
        int nd = i >> 5;
        if (n0 + nd < NN) h1u[(size_t)(n0 + nd) * 32 + (i & 31)] = ((const uint*)sO)[i];
    }
}

// ---------- Layer 2 aggregation: node-per-16-lane-group, 4 ch/lane (R10 base),
// p12 merged loads + dmin full/tail split + grid-stride at 8 blocks/CU
// + unroll-4 full phase at 256-thread blocks (the SINGLE-variable MLP test:
// 4 p-loads under one waitcnt, 4 gathers under one, amortizing the ~600cy
// chain over 4 edges instead of 2).
__global__ __launch_bounds__(256) void aggr2_kernel(
    const uint* __restrict__ h1u,
    const uint* __restrict__ p0, const uint* __restrict__ p12,
    const int* __restrict__ offs,
    const float* __restrict__ We2, const float* __restrict__ be2,
    uint* __restrict__ zb)
{
    const int tid = threadIdx.x;
    const int lane = tid & 63;
    const int wv = tid >> 6;             // wave 0..3
    const int grp = lane >> 4;           // node group 0..3 within wave
    const int cl = lane & 15;            // channel quad: ch 4cl..4cl+3

    // per-lane weights: columns 4cl..4cl+3 of We2[4][64], as 2 float2v per row
    float2v wA[4], wB[4], bA, bB;
    #pragma unroll
    for (int k = 0; k < 4; ++k) {
        const float4 w4 = *(const float4*)&We2[k * 64 + 4 * cl];
        wA[k][0] = w4.x; wA[k][1] = w4.y;
        wB[k][0] = w4.z; wB[k][1] = w4.w;
    }
    {
        const float4 b4 = *(const float4*)&be2[4 * cl];
        bA[0] = b4.x; bA[1] = b4.y;
        bB[0] = b4.z; bB[1] = b4.w;
    }

    #define EDGE_MATH(pey, pez, gg, tAo, tBo)                               \
    {                                                                       \
        float2v bvA = bA + bf2f_lo(pey) * wA[0] + bf2f_hi(pey) * wA[1]      \
                    + bf2f_lo(pez) * wA[2] + bf2f_hi(pez) * wA[3];          \
        float2v bvB = bB + bf2f_lo(pey) * wB[0] + bf2f_hi(pey) * wB[1]      \
                    + bf2f_lo(pez) * wB[2] + bf2f_hi(pez) * wB[3];          \
        tAo[0] = fmaxf(bf2f_lo((gg).x) + bvA[0], 0.f);                      \
        tAo[1] = fmaxf(bf2f_hi((gg).x) + bvA[1], 0.f);                      \
        tBo[0] = fmaxf(bf2f_lo((gg).y) + bvB[0], 0.f);                      \
        tBo[1] = fmaxf(bf2f_hi((gg).y) + bvB[1], 0.f);                      \
    }

    for (int nb = blockIdx.x; nb < NBLK2; nb += GRID2) {
        const int n = nb * NPB + wv * 4 + grp;   // NN % 16 == 0, always valid

        const int off = offs[n];
        const int deg = offs[n + 1] - off;
        const int degm1 = (deg > 0) ? deg - 1 : 0;
        const int offC = (deg > 0) ? off : 0;    // deg==0: clamp to a safe index
        // wave-uniform bounds: min/max degree over the wave's 4 groups
        int dmax = deg, dmin = deg;
        dmax = max(dmax, __shfl_xor(dmax, 16));
        dmax = max(dmax, __shfl_xor(dmax, 32));
        dmin = min(dmin, __shfl_xor(dmin, 16));
        dmin = min(dmin, __shfl_xor(dmin, 32));

        float2v accA = {0.f, 0.f}, accB = {0.f, 0.f};
        const float2v zero2 = {0.f, 0.f};

        int j = 0;
        // full phase, unroll-4: 4 independent chains, no clamping, no predication
        for (; j + 4 <= dmin; j += 4) {
            const int e0 = off + j;
            const uint r00 = p0[e0], r01 = p0[e0 + 1], r02 = p0[e0 + 2], r03 = p0[e0 + 3];
            const uint2 pe0 = *(const uint2*)&p12[2 * (size_t)e0];
            const uint2 pe1 = *(const uint2*)&p12[2 * (size_t)e0 + 2];
            const uint2 pe2 = *(const uint2*)&p12[2 * (size_t)e0 + 4];
            const uint2 pe3 = *(const uint2*)&p12[2 * (size_t)e0 + 6];
            const uint2 g0 = *(const uint2*)&h1u[((size_t)(r00 & 0xFFFFu) << 5) + 2 * cl];
            const uint2 g1 = *(const uint2*)&h1u[((size_t)(r01 & 0xFFFFu) << 5) + 2 * cl];
            const uint2 g2 = *(const uint2*)&h1u[((size_t)(r02 & 0xFFFFu) << 5) + 2 * cl];
            const uint2 g3 = *(const uint2*)&h1u[((size_t)(r03 & 0xFFFFu) << 5) + 2 * cl];
            float2v tA, tB;
            EDGE_MATH(pe0.x, pe0.y, g0, tA, tB); accA += tA; accB += tB;
            EDGE_MATH(pe1.x, pe1.y, g1, tA, tB); accA += tA; accB += tB;
            EDGE_MATH(pe2.x, pe2.y, g2, tA, tB); accA += tA; accB += tB;
            EDGE_MATH(pe3.x, pe3.y, g3, tA, tB); accA += tA; accB += tB;
        }
        // full phase remainder, unroll-2
        for (; j + 2 <= dmin; j += 2) {
            const int e0 = off + j, e1 = off + j + 1;
            const uint r00 = p0[e0];
            const uint2 pe0 = *(const uint2*)&p12[2 * (size_t)e0];
            const uint r01 = p0[e1];
            const uint2 pe1 = *(const uint2*)&p12[2 * (size_t)e1];
            const uint2 g0 = *(const uint2*)&h1u[((size_t)(r00 & 0xFFFFu) << 5) + 2 * cl];
            const uint2 g1 = *(const uint2*)&h1u[((size_t)(r01 & 0xFFFFu) << 5) + 2 * cl];
            float2v tA, tB;
            EDGE_MATH(pe0.x, pe0.y, g0, tA, tB);
            accA += tA; accB += tB;
            EDGE_MATH(pe1.x, pe1.y, g1, tA, tB);
            accA += tA; accB += tB;
        }
        // tail phase: predicated (j in [full-end, dmax))
        for (; j + 2 <= dmax; j += 2) {
            const bool q0 = (j < deg), q1 = (j + 1 < deg);
            const int e0 = offC + (q0 ? j : degm1);
            const int e1 = offC + (q1 ? j + 1 : degm1);
            const uint r00 = p0[e0];
            const uint2 pe0 = *(const uint2*)&p12[2 * (size_t)e0];
            const uint r01 = p0[e1];
            const uint2 pe1 = *(const uint2*)&p12[2 * (size_t)e1];
            const uint2 g0 = *(const uint2*)&h1u[((size_t)(r00 & 0xFFFFu) << 5) + 2 * cl];
            const uint2 g1 = *(const uint2*)&h1u[((size_t)(r01 & 0xFFFFu) << 5) + 2 * cl];
            float2v tA, tB;
            EDGE_MATH(pe0.x, pe0.y, g0, tA, tB);
            accA += q0 ? tA : zero2;
            accB += q0 ? tB : zero2;
            EDGE_MATH(pe1.x, pe1.y, g1, tA, tB);
            accA += q1 ? tA : zero2;
            accB += q1 ? tB : zero2;
        }
        if (j < dmax) {                           // odd remainder step
            const bool q0 = (j < deg);
            const int e0 = offC + (q0 ? j : degm1);
            const uint r00 = p0[e0];
            const uint2 pe0 = *(const uint2*)&p12[2 * (size_t)e0];
            const uint2 g0 = *(const uint2*)&h1u[((size_t)(r00 & 0xFFFFu) << 5) + 2 * cl];
            float2v tA, tB;
            EDGE_MATH(pe0.x, pe0.y, g0, tA, tB);
            accA += q0 ? tA : zero2;
            accB += q0 ? tB : zero2;
        }

        // epilogue: z = h1[n] + acc, pack bf16x2, store 2 dwords per lane
        // (consecutive groups = consecutive nodes -> contiguous 256B per wave)
        const uint2 hw = *(const uint2*)&h1u[(size_t)n * 32 + 2 * cl];
        uint o0 = f2bf(bf2f_lo(hw.x) + accA[0]) | (f2bf(bf2f_hi(hw.x) + accA[1]) << 16);
        uint o1 = f2bf(bf2f_lo(hw.y) + accB[0]) | (f2bf(bf2f_hi(hw.y) + accB[1]) << 16);
        uint2 ov; ov.x = o0; ov.y = o1;
        *(uint2*)&zb[(size_t)n * 32 + 2 * cl] = ov;
    }
    #undef EDGE_MATH
}

// ---------- Layer 2 MLP via MFMA + segmented-reduction pooling (R12-proven) ----------
__global__ __launch_bounds__(256) void mlp2_kernel(
    const uint* __restrict__ zb,
    const float* __restrict__ W2a, const float* __restrict__ b2a,
    const float* __restrict__ W2b, const float* __restrict__ b2b,
    const int* __restrict__ batch,
    float* __restrict__ sums, float* __restrict__ cnt)
{
    __shared__ __align__(16) ushort sT[64 * MSTRIDE];
    __shared__ float sH[64 * 64];
    __shared__ int sB[64];
    __shared__ float pbuf[4][64];
    __shared__ int pcnt[4];
    const int t = threadIdx.x;
    const int w = t >> 6, lane = t & 63;
    const int qm = lane & 15, quad = lane >> 4;
    const int n0 = blockIdx.x * 64;
    const int node = n0 + w * 16 + qm;
    const int nv = (NN - n0 < 64) ? (NN - n0) : 64;

    if (t < 64) sB[t] = (n0 + t < NN) ? batch[n0 + t] : -2;

    short8 wa[2][4], wb[2][4];
    #pragma unroll
    for (int s = 0; s < 2; ++s)
        #pragma unroll
        for (int nt = 0; nt < 4; ++nt) {
            short8 va, vb;
            #pragma unroll
            for (int j = 0; j < 8; ++j) {
                int k = s * 32 + quad * 8 + j, n = nt * 16 + qm;
                va[j] = (short)f2bf(W2a[k * 64 + n]);
                vb[j] = (short)f2bf(W2b[k * 64 + n]);
            }
            wa[s][nt] = va; wb[s][nt] = vb;
        }
    float ba[4], bb[4];
    #pragma unroll
    for (int nt = 0; nt < 4; ++nt) { ba[nt] = b2a[nt * 16 + qm]; bb[nt] = b2b[nt * 16 + qm]; }

    float4v acc[4];
    #pragma unroll
    for (int nt = 0; nt < 4; ++nt) acc[nt] = (float4v){0.f, 0.f, 0.f, 0.f};
    #pragma unroll
    for (int s = 0; s < 2; ++s) {
        uint4 zw = (node < NN) ? *(const uint4*)&zb[(size_t)node * 32 + s * 16 + quad * 4]
                               : make_uint4(0, 0, 0, 0);
        short8 af;
        *(uint4*)&af = zw;
        #pragma unroll
        for (int nt = 0; nt < 4; ++nt)
            acc[nt] = __builtin_amdgcn_mfma_f32_16x16x32_bf16(af, wa[s][nt], acc[nt], 0, 0, 0);
    }
    #pragma unroll
    for (int nt = 0; nt < 4; ++nt)
        #pragma unroll
        for (int r = 0; r < 4; ++r)
            sT[(w * 16 + quad * 4 + r) * MSTRIDE + nt * 16 + qm] =
                (ushort)f2bf(fmaxf(acc[nt][r] + ba[nt], 0.f));
    __syncthreads();

    #pragma unroll
    for (int nt = 0; nt < 4; ++nt) acc[nt] = (float4v){0.f, 0.f, 0.f, 0.f};
    #pragma unroll
    for (int s = 0; s < 2; ++s) {
        short8 af = *(const short8*)&sT[(w * 16 + qm) * MSTRIDE + s * 32 + quad * 8];
        #pragma unroll
        for (int nt = 0; nt < 4; ++nt)
            acc[nt] = __builtin_amdgcn_mfma_f32_16x16x32_bf16(af, wb[s][nt], acc[nt], 0, 0, 0);
    }
    #pragma unroll
    for (int nt = 0; nt < 4; ++nt)
        #pragma unroll
        for (int r = 0; r < 4; ++r)
            sH[(w * 16 + quad * 4 + r) * 64 + nt * 16 + qm] = fmaxf(acc[nt][r] + bb[nt], 0.f);
    __syncthreads();

    const int glo = sB[0];
    const int ghi = sB[nv - 1];
    const int c = t >> 6, d = t & 63;
    for (int g = glo; g <= ghi; ++g) {
        float p = 0.f;
        int lc = 0;
        #pragma unroll 4
        for (int i = 0; i < 16; ++i) {
            int nd = c * 16 + i;
            if (sB[nd] == g) { p += sH[nd * 64 + d]; ++lc; }
        }
        pbuf[c][d] = p;
        if (d == 0) pcnt[c] = lc;
        __syncthreads();
        int tc = pcnt[0] + pcnt[1] + pcnt[2] + pcnt[3];
        if (tc > 0) {
            if (c == 0) {
                float tot = pbuf[0][d] + pbuf[1][d] + pbuf[2][d] + pbuf[3][d];
                atomicAdd(&sums[(size_t)g * 64 + d], tot);
            }
            if (t == 0) atomicAdd(&cnt[g], (float)tc);
        }
        __syncthreads();
    }
}

// ---------- FC ----------
__global__ __launch_bounds__(256) void fc_kernel(
    const float* __restrict__ sums, const float* __restrict__ cnt,
    const float* __restrict__ Wfc, const float* __restrict__ bfc,
    float* __restrict__ out)
{
    int gid = blockIdx.x * blockDim.x + threadIdx.x;
    if (gid >= NG * 12) return;
    int g = gid / 12, jj = gid - g * 12;
    float inv = 1.f / fmaxf(cnt[g], 1.f);
    float acc = bfc[jj];
    #pragma unroll 8
    for (int k = 0; k < 64; ++k) acc += sums[(size_t)g * 64 + k] * inv * Wfc[k * 12 + jj];
    out[gid] = acc;
}

extern "C" void kernel_launch(void* const* d_in, const int* in_sizes, int n_in,
                              void* d_out, int out_size, void* d_ws, size_t ws_size,
                              hipStream_t stream)
{
    (void)in_sizes; (void)n_in; (void)out_size; (void)ws_size;
    const float*  x    = (const float*)d_in[0];
    const float4* ea   = (const float4*)d_in[1];
    const int*    eidx = (const int*)d_in[2];
    const int*    batch= (const int*)d_in[3];
    const float*  We1  = (const float*)d_in[4];
    const float*  be1  = (const float*)d_in[5];
    const float*  W1a  = (const float*)d_in[6];
    const float*  b1a  = (const float*)d_in[7];
    const float*  W1b  = (const float*)d_in[8];
    const float*  b1b  = (const float*)d_in[9];
    const float*  We2  = (const float*)d_in[10];
    const float*  be2  = (const float*)d_in[11];
    const float*  W2a  = (const float*)d_in[12];
    const float*  b2a  = (const float*)d_in[13];
    const float*  W2b  = (const float*)d_in[14];
    const float*  b2b  = (const float*)d_in[15];
    const float*  Wfc  = (const float*)d_in[16];
    const float*  bfc  = (const float*)d_in[17];
    float* out = (float*)d_out;
    float* ws  = (float*)d_ws;

    int*   bcnt  = (int*)(ws + OFF_BCNT);
    float* sums  = ws + OFF_SUMS;
    float* cnt   = ws + OFF_CNT;
    int*   bbase = (int*)(ws + OFF_BBASE);
    int*   bcur  = (int*)(ws + OFF_BCUR);
    int*   offs  = (int*)(ws + OFF_OFFS);
    uint*  p0    = (uint*)(ws + OFF_P0);
    uint*  p12   = (uint*)(ws + OFF_P12);
    float* z1    = ws + OFF_Z1;
    uint*  h1u   = (uint*)(ws + OFF_H1);
    uint*  zb    = (uint*)(ws + OFF_Z);

    hipMemsetAsync(d_ws, 0, (size_t)ZERO_UNITS * 4, stream);

    bhist_kernel<<<256, 256, 0, stream>>>(eidx, bcnt);
    bscan_kernel<<<1, 256, 0, stream>>>(bcnt, bbase, bcur);
    bin_kernel  <<<NTILE, 256, 0, stream>>>(eidx, ea, bcur, p0, p12);
    build_kernel<<<NB2, 256, 0, stream>>>(bbase, bcnt, offs, p0, p12);
    aggr1_kernel<<<2500, 256, 0, stream>>>(x, p0, p12, offs, We1, be1, z1);
    node1_kernel<<<(NN + 63) / 64, 256, 0, stream>>>(z1, W1a, b1a, W1b, b1b, h1u);
    aggr2_kernel<<<GRID2, 256, 0, stream>>>(h1u, p0, p12, offs, We2, be2, zb);
    mlp2_kernel <<<(NN + 63) / 64, 256, 0, stream>>>(zb, W2a, b2a, W2b, b2b, batch, sums, cnt);
    fc_kernel   <<<(NG * 12 + 255) / 256, 256, 0, stream>>>(sums, cnt, Wfc, bfc, out);
}